// Round 1
// baseline (804.420 us; speedup 1.0000x reference)
//
#include <hip/hip_runtime.h>

#define S_LEN 8192
#define D_DIM 2048
#define HD 128
#define QT 64
#define KT 64

// ---------------- projection: out = x @ w ----------------
// one 128-row tile per block; blockIdx.y selects {q,k,v}
__global__ __launch_bounds__(256)
void proj_kernel(const float* __restrict__ x,
                 const float* __restrict__ wq, const float* __restrict__ wk,
                 const float* __restrict__ wv,
                 float* __restrict__ q, float* __restrict__ k, float* __restrict__ v)
{
  const float* __restrict__ w = (blockIdx.y == 0) ? wq : (blockIdx.y == 1) ? wk : wv;
  float* __restrict__ out = (blockIdx.y == 0) ? q : (blockIdx.y == 1) ? k : v;
  const int mt = blockIdx.x;

  __shared__ float xs[32][132];   // transposed x tile: xs[kk][r], padded
  __shared__ float wsm[32][128];  // w tile: wsm[kk][c]

  const int t  = threadIdx.x;
  const int rg = t >> 4;   // 0..15
  const int cg = t & 15;   // 0..15

  float acc[8][8];
#pragma unroll
  for (int i = 0; i < 8; ++i)
#pragma unroll
    for (int j = 0; j < 8; ++j) acc[i][j] = 0.f;

  for (int kt = 0; kt < D_DIM; kt += 32) {
    // stage x tile transposed (coalesced global read, scalar LDS scatter)
#pragma unroll
    for (int i = 0; i < 4; ++i) {
      int idx = t + i * 256;        // 0..1023
      int row = idx >> 3;           // 8 float4 per row (BK=32)
      int k4  = idx & 7;
      float4 xv = *(const float4*)(x + (size_t)(mt * 128 + row) * D_DIM + kt + k4 * 4);
      xs[k4*4+0][row] = xv.x;
      xs[k4*4+1][row] = xv.y;
      xs[k4*4+2][row] = xv.z;
      xs[k4*4+3][row] = xv.w;
    }
    // stage w tile (natural layout)
#pragma unroll
    for (int i = 0; i < 4; ++i) {
      int idx = t + i * 256;
      int row = idx >> 5;           // 32 float4 per row (128 cols)
      int c4  = idx & 31;
      *(float4*)&wsm[row][c4*4] = *(const float4*)(w + (size_t)(kt + row) * HD + c4 * 4);
    }
    __syncthreads();
#pragma unroll 8
    for (int kk = 0; kk < 32; ++kk) {
      float a[8], b[8];
      *(float4*)&a[0] = *(const float4*)&xs[kk][4*rg];
      *(float4*)&a[4] = *(const float4*)&xs[kk][64 + 4*rg];
      *(float4*)&b[0] = *(const float4*)&wsm[kk][4*cg];
      *(float4*)&b[4] = *(const float4*)&wsm[kk][64 + 4*cg];
#pragma unroll
      for (int i = 0; i < 8; ++i)
#pragma unroll
        for (int j = 0; j < 8; ++j)
          acc[i][j] = fmaf(a[i], b[j], acc[i][j]);
    }
    __syncthreads();
  }
  // store: rows split {4rg.., 64+4rg..}, cols split {4cg.., 64+4cg..}
#pragma unroll
  for (int ih = 0; ih < 2; ++ih)
#pragma unroll
    for (int i = 0; i < 4; ++i) {
      int r = mt * 128 + ih * 64 + 4 * rg + i;
#pragma unroll
      for (int jh = 0; jh < 2; ++jh) {
        float4 o;
        o.x = acc[ih*4+i][jh*4+0];
        o.y = acc[ih*4+i][jh*4+1];
        o.z = acc[ih*4+i][jh*4+2];
        o.w = acc[ih*4+i][jh*4+3];
        *(float4*)(out + (size_t)r * HD + jh * 64 + 4 * cg) = o;
      }
    }
}

// ---------------- causal flash attention (fp32), partials per (tile, chunk) ----------------
// grid = 256 blocks: pair p = bid>>2 handles q-tiles {p, 127-p}; chunk = bid&3 takes
// kv-tiles j ≡ chunk (mod 4). Writes unnormalized partial (o, m, l).
__global__ __launch_bounds__(256)
void attn_kernel(const float* __restrict__ q, const float* __restrict__ k,
                 const float* __restrict__ v,
                 float* __restrict__ part_o, float* __restrict__ part_ml)
{
  __shared__ float qs[QT][129];    // natural layout, odd stride for conflict-free reads
  __shared__ float ks[KT][129];
  __shared__ float vs[KT][128];
  __shared__ float pT[KT][68];     // transposed probs: pT[col][row], 16B-aligned stride

  const int t  = threadIdx.x;
  const int rg = t >> 4;           // 0..15 -> rows 4rg..4rg+3
  const int cg = t & 15;           // 0..15 -> cols 4cg..4cg+3
  const int pairId = blockIdx.x >> 2;
  const int chunk  = blockIdx.x & 3;

  for (int half = 0; half < 2; ++half) {
    const int tile = (half == 0) ? pairId : 127 - pairId;

    // stage q tile
#pragma unroll
    for (int i = 0; i < 8; ++i) {
      int idx = t + i * 256;
      int r  = idx >> 5;
      int d4 = idx & 31;
      float4 val = *(const float4*)(q + ((size_t)tile * QT + r) * HD + d4 * 4);
      qs[r][d4*4+0] = val.x;
      qs[r][d4*4+1] = val.y;
      qs[r][d4*4+2] = val.z;
      qs[r][d4*4+3] = val.w;
    }

    float m_r[4], l_r[4], o_acc[4][8];
#pragma unroll
    for (int i = 0; i < 4; ++i) {
      m_r[i] = -1e30f;
      l_r[i] = 0.f;
#pragma unroll
      for (int jo = 0; jo < 8; ++jo) o_acc[i][jo] = 0.f;
    }
    __syncthreads();

    for (int j = chunk; j <= tile; j += 4) {
      // stage k (natural) and v
#pragma unroll
      for (int i = 0; i < 8; ++i) {
        int idx = t + i * 256;
        int r  = idx >> 5;
        int d4 = idx & 31;
        float4 kv = *(const float4*)(k + ((size_t)j * KT + r) * HD + d4 * 4);
        ks[r][d4*4+0] = kv.x;
        ks[r][d4*4+1] = kv.y;
        ks[r][d4*4+2] = kv.z;
        ks[r][d4*4+3] = kv.w;
        float4 vv = *(const float4*)(v + ((size_t)j * KT + r) * HD + d4 * 4);
        *(float4*)&vs[r][d4*4] = vv;
      }
      __syncthreads();

      // scores: 4x4 micro-tile per thread
      float sc[4][4];
#pragma unroll
      for (int i = 0; i < 4; ++i)
#pragma unroll
        for (int jj = 0; jj < 4; ++jj) sc[i][jj] = 0.f;

#pragma unroll 4
      for (int d = 0; d < HD; ++d) {
        float a[4], b[4];
#pragma unroll
        for (int i = 0; i < 4; ++i) a[i] = qs[4*rg + i][d];
#pragma unroll
        for (int jj = 0; jj < 4; ++jj) b[jj] = ks[4*cg + jj][d];
#pragma unroll
        for (int i = 0; i < 4; ++i)
#pragma unroll
          for (int jj = 0; jj < 4; ++jj)
            sc[i][jj] = fmaf(a[i], b[jj], sc[i][jj]);
      }

      const float scale = 0.08838834764831843f;  // 1/sqrt(128)
#pragma unroll
      for (int i = 0; i < 4; ++i)
#pragma unroll
        for (int jj = 0; jj < 4; ++jj) sc[i][jj] *= scale;

      if (j == tile) {  // causal mask on diagonal tile
#pragma unroll
        for (int i = 0; i < 4; ++i)
#pragma unroll
          for (int jj = 0; jj < 4; ++jj)
            if (4*cg + jj > 4*rg + i) sc[i][jj] = -1e30f;
      }

      // online softmax update (row reductions across the 16 cg-lanes)
#pragma unroll
      for (int i = 0; i < 4; ++i) {
        float rm = fmaxf(fmaxf(sc[i][0], sc[i][1]), fmaxf(sc[i][2], sc[i][3]));
#pragma unroll
        for (int off = 1; off < 16; off <<= 1)
          rm = fmaxf(rm, __shfl_xor(rm, off, 64));
        float mnew = fmaxf(m_r[i], rm);
        float corr = __expf(m_r[i] - mnew);
        float rs = 0.f;
#pragma unroll
        for (int jj = 0; jj < 4; ++jj) {
          sc[i][jj] = __expf(sc[i][jj] - mnew);
          rs += sc[i][jj];
        }
#pragma unroll
        for (int off = 1; off < 16; off <<= 1)
          rs += __shfl_xor(rs, off, 64);
        l_r[i] = l_r[i] * corr + rs;
        m_r[i] = mnew;
#pragma unroll
        for (int jo = 0; jo < 8; ++jo) o_acc[i][jo] *= corr;
      }

      // write probs transposed for PV
#pragma unroll
      for (int jj = 0; jj < 4; ++jj)
#pragma unroll
        for (int i = 0; i < 4; ++i)
          pT[4*cg + jj][4*rg + i] = sc[i][jj];
      __syncthreads();

      // PV: o += p @ v
#pragma unroll 2
      for (int jj2 = 0; jj2 < KT; ++jj2) {
        float pr[4], vv0[4], vv1[4];
        *(float4*)&pr[0]  = *(const float4*)&pT[jj2][4*rg];
        *(float4*)&vv0[0] = *(const float4*)&vs[jj2][4*cg];
        *(float4*)&vv1[0] = *(const float4*)&vs[jj2][64 + 4*cg];
#pragma unroll
        for (int i = 0; i < 4; ++i) {
#pragma unroll
          for (int jo = 0; jo < 4; ++jo) {
            o_acc[i][jo]     = fmaf(pr[i], vv0[jo], o_acc[i][jo]);
            o_acc[i][jo + 4] = fmaf(pr[i], vv1[jo], o_acc[i][jo + 4]);
          }
        }
      }
      __syncthreads();
    }

    // write partials (unnormalized o, plus m and l)
    const int base = tile * 4 + chunk;
#pragma unroll
    for (int i = 0; i < 4; ++i) {
      int r = 4 * rg + i;
      float4 o0, o1;
      o0.x = o_acc[i][0]; o0.y = o_acc[i][1]; o0.z = o_acc[i][2]; o0.w = o_acc[i][3];
      o1.x = o_acc[i][4]; o1.y = o_acc[i][5]; o1.z = o_acc[i][6]; o1.w = o_acc[i][7];
      *(float4*)&part_o[((size_t)base * QT + r) * HD + 4 * cg]      = o0;
      *(float4*)&part_o[((size_t)base * QT + r) * HD + 64 + 4 * cg] = o1;
    }
    if (cg == 0) {
#pragma unroll
      for (int i = 0; i < 4; ++i) {
        part_ml[base * 128 + 4 * rg + i]      = m_r[i];
        part_ml[base * 128 + 64 + 4 * rg + i] = l_r[i];
      }
    }
    __syncthreads();
  }
}

// ---------------- merge the 4 column-chunk partials ----------------
__global__ __launch_bounds__(128)
void merge_kernel(const float* __restrict__ part_o, const float* __restrict__ part_ml,
                  float* __restrict__ out)
{
  const int row  = blockIdx.x;
  const int tile = row >> 6;
  const int r    = row & 63;
  const int c    = threadIdx.x;

  float m[4], l[4];
  float mstar = -3e38f;
#pragma unroll
  for (int s = 0; s < 4; ++s) {
    m[s] = part_ml[(tile * 4 + s) * 128 + r];
    l[s] = part_ml[(tile * 4 + s) * 128 + 64 + r];
    mstar = fmaxf(mstar, m[s]);
  }
  float num = 0.f, den = 0.f;
#pragma unroll
  for (int s = 0; s < 4; ++s) {
    float wgt = __expf(m[s] - mstar);
    den += l[s] * wgt;
    num += wgt * part_o[((size_t)(tile * 4 + s) * QT + r) * HD + c];
  }
  out[(size_t)row * HD + c] = num / den;
}

extern "C" void kernel_launch(void* const* d_in, const int* in_sizes, int n_in,
                              void* d_out, int out_size, void* d_ws, size_t ws_size,
                              hipStream_t stream)
{
  const float* x  = (const float*)d_in[0];
  const float* wq = (const float*)d_in[1];
  const float* wk = (const float*)d_in[2];
  const float* wv = (const float*)d_in[3];
  float* out = (float*)d_out;

  float* ws = (float*)d_ws;
  float* q       = ws;                                   // 8192*128
  float* k       = q + (size_t)S_LEN * HD;               // 8192*128
  float* v       = k + (size_t)S_LEN * HD;               // 8192*128
  float* part_o  = v + (size_t)S_LEN * HD;               // 512*64*128
  float* part_ml = part_o + (size_t)512 * QT * HD;       // 512*128

  proj_kernel<<<dim3(64, 3), 256, 0, stream>>>(x, wq, wk, wv, q, k, v);
  attn_kernel<<<dim3(256), 256, 0, stream>>>(q, k, v, part_o, part_ml);
  merge_kernel<<<dim3(8192), 128, 0, stream>>>(part_o, part_ml, out);
}

// Round 2
// 455.958 us; speedup vs baseline: 1.7642x; 1.7642x over previous
//
#include <hip/hip_runtime.h>

#define S_LEN 8192
#define D_DIM 2048
#define HD    128
#define NT    128      // number of 64-row tiles
#define QT    64
#define NCH   4        // kv chunks (flash-decoding split)

typedef __attribute__((ext_vector_type(8))) short bf16x8;
typedef __attribute__((ext_vector_type(4))) float f32x4;

__device__ __forceinline__ unsigned short f2bf(float f) {
  unsigned int u = __float_as_uint(f);
  u += 0x7fffu + ((u >> 16) & 1u);
  return (unsigned short)(u >> 16);
}
__device__ __forceinline__ float bf2f(unsigned short h) {
  return __uint_as_float(((unsigned int)h) << 16);
}

__device__ __forceinline__ void glds16(const void* g, const short* l) {
  __builtin_amdgcn_global_load_lds(
      (const __attribute__((address_space(1))) void*)g,
      (__attribute__((address_space(3))) void*)l, 16, 0, 0);
}

// ---------------- projection: fp32 GEMM, epilogue emits split-bf16 ----------------
// q gets 1/sqrt(128) folded in; q/k written as (hi,lo) bf16 row-major; v written bf16 TRANSPOSED [HD][S]
__global__ __launch_bounds__(256)
void proj_kernel(const float* __restrict__ x,
                 const float* __restrict__ wq, const float* __restrict__ wk,
                 const float* __restrict__ wv,
                 unsigned short* __restrict__ q_hi, unsigned short* __restrict__ q_lo,
                 unsigned short* __restrict__ k_hi, unsigned short* __restrict__ k_lo,
                 unsigned short* __restrict__ vT)
{
  const int mode = blockIdx.y;
  const float* __restrict__ w = (mode == 0) ? wq : (mode == 1) ? wk : wv;
  const int mt = blockIdx.x;

  __shared__ float xs[32][132];
  __shared__ float wsm[32][128];

  const int t  = threadIdx.x;
  const int rg = t >> 4;
  const int cg = t & 15;

  float acc[8][8];
#pragma unroll
  for (int i = 0; i < 8; ++i)
#pragma unroll
    for (int j = 0; j < 8; ++j) acc[i][j] = 0.f;

  for (int kt = 0; kt < D_DIM; kt += 32) {
#pragma unroll
    for (int i = 0; i < 4; ++i) {
      int idx = t + i * 256;
      int row = idx >> 3;
      int k4  = idx & 7;
      float4 xv = *(const float4*)(x + (size_t)(mt * 128 + row) * D_DIM + kt + k4 * 4);
      xs[k4*4+0][row] = xv.x;
      xs[k4*4+1][row] = xv.y;
      xs[k4*4+2][row] = xv.z;
      xs[k4*4+3][row] = xv.w;
    }
#pragma unroll
    for (int i = 0; i < 4; ++i) {
      int idx = t + i * 256;
      int row = idx >> 5;
      int c4  = idx & 31;
      *(float4*)&wsm[row][c4*4] = *(const float4*)(w + (size_t)(kt + row) * HD + c4 * 4);
    }
    __syncthreads();
#pragma unroll 8
    for (int kk = 0; kk < 32; ++kk) {
      float a[8], b[8];
      *(float4*)&a[0] = *(const float4*)&xs[kk][4*rg];
      *(float4*)&a[4] = *(const float4*)&xs[kk][64 + 4*rg];
      *(float4*)&b[0] = *(const float4*)&wsm[kk][4*cg];
      *(float4*)&b[4] = *(const float4*)&wsm[kk][64 + 4*cg];
#pragma unroll
      for (int i = 0; i < 8; ++i)
#pragma unroll
        for (int j = 0; j < 8; ++j)
          acc[i][j] = fmaf(a[i], b[j], acc[i][j]);
    }
    __syncthreads();
  }

  if (mode < 2) {
    const float scale = (mode == 0) ? 0.08838834764831843f : 1.0f;
    unsigned short* __restrict__ oh = (mode == 0) ? q_hi : k_hi;
    unsigned short* __restrict__ ol = (mode == 0) ? q_lo : k_lo;
#pragma unroll
    for (int ih = 0; ih < 2; ++ih)
#pragma unroll
      for (int i = 0; i < 4; ++i) {
        int r = mt * 128 + ih * 64 + 4 * rg + i;
#pragma unroll
        for (int jh = 0; jh < 2; ++jh) {
          ushort4 hv, lvec;
#pragma unroll
          for (int jj = 0; jj < 4; ++jj) {
            float val = acc[ih*4+i][jh*4+jj] * scale;
            unsigned short hb = f2bf(val);
            float lo = val - bf2f(hb);
            ((unsigned short*)&hv)[jj]   = hb;
            ((unsigned short*)&lvec)[jj] = f2bf(lo);
          }
          *(ushort4*)(oh + (size_t)r * HD + jh * 64 + 4 * cg) = hv;
          *(ushort4*)(ol + (size_t)r * HD + jh * 64 + 4 * cg) = lvec;
        }
      }
  } else {
    // v: write bf16 transposed vT[d][s]
#pragma unroll
    for (int jh = 0; jh < 2; ++jh)
#pragma unroll
      for (int jj = 0; jj < 4; ++jj) {
        int c = jh * 64 + 4 * cg + jj;
#pragma unroll
        for (int ih = 0; ih < 2; ++ih) {
          ushort4 ov;
#pragma unroll
          for (int i = 0; i < 4; ++i)
            ((unsigned short*)&ov)[i] = f2bf(acc[ih*4+i][jh*4+jj]);
          *(ushort4*)(vT + (size_t)c * S_LEN + mt * 128 + ih * 64 + 4 * rg) = ov;
        }
      }
  }
}

// ---------------- MFMA flash attention (split-bf16 QK^T, bf16 PV) ----------------
// 64 pairs x 4 chunks = 256 blocks; 4 waves of 16 q-rows each; partials (o,m,l) per (tile,chunk)
__global__ __launch_bounds__(256)
void attn_kernel(const unsigned short* __restrict__ q_hi, const unsigned short* __restrict__ q_lo,
                 const unsigned short* __restrict__ k_hi, const unsigned short* __restrict__ k_lo,
                 const unsigned short* __restrict__ vT,
                 float* __restrict__ part_o, float* __restrict__ part_ml)
{
  extern __shared__ short smem[];
  short* ls_kh = smem;                 // 2 x 64x128 bf16 (XOR-swizzled)
  short* ls_kl = ls_kh + 16384;
  short* ls_v  = ls_kl + 16384;        // 2 x 128x64 bf16 (v^T, XOR-swizzled)
  short* ls_p  = ls_v + 16384;         // 4 waves x [16][72] bf16

  const int t   = threadIdx.x;
  const int w   = t >> 6;
  const int ln  = t & 63;
  const int cl  = ln & 15;
  const int g4  = ln >> 4;
  const int pairId  = blockIdx.x >> 2;
  const int chunkId = blockIdx.x & 3;

  short* pw = ls_p + w * (16 * 72);

  auto stage = [&](int j, int buf) {
    const unsigned short* gkh = k_hi + (size_t)j * QT * HD;
    const unsigned short* gkl = k_lo + (size_t)j * QT * HD;
    const unsigned short* gv  = vT + (size_t)j * QT;
    const short* lkh = ls_kh + buf * 8192;
    const short* lkl = ls_kl + buf * 8192;
    const short* lv  = ls_v  + buf * 8192;
#pragma unroll
    for (int i = 0; i < 4; ++i) {
      int slot = w * 256 + i * 64 + ln;
      int row = slot >> 4, sc = slot & 15;
      int c16 = sc ^ (row & 7);
      glds16(gkh + row * HD + c16 * 8, lkh + (w * 256 + i * 64) * 8);
      glds16(gkl + row * HD + c16 * 8, lkl + (w * 256 + i * 64) * 8);
    }
#pragma unroll
    for (int i = 0; i < 4; ++i) {
      int slot = w * 256 + i * 64 + ln;
      int d = slot >> 3, sc = slot & 7;
      int c = sc ^ (d & 7);
      glds16(gv + (size_t)d * S_LEN + c * 8, lv + (w * 256 + i * 64) * 8);
    }
  };

  for (int hh = 0; hh < 2; ++hh) {
    const int tile = hh ? (NT - 1 - pairId) : pairId;

    // Q fragments in registers (A-layout: row = cl, k = g4*8 + e)
    bf16x8 qh[4], ql[4];
    {
      const size_t qoff = ((size_t)tile * QT + w * 16 + cl) * HD + g4 * 8;
#pragma unroll
      for (int kc = 0; kc < 4; ++kc) {
        qh[kc] = *(const bf16x8*)(q_hi + qoff + kc * 32);
        ql[kc] = *(const bf16x8*)(q_lo + qoff + kc * 32);
      }
    }

    float m_r[4], l_r[4];
    f32x4 o_acc[8];
#pragma unroll
    for (int r = 0; r < 4; ++r) { m_r[r] = -1e30f; l_r[r] = 0.f; }
#pragma unroll
    for (int c = 0; c < 8; ++c) o_acc[c] = f32x4{0.f, 0.f, 0.f, 0.f};

    if (chunkId <= tile) {
      int cur = 0;
      stage(chunkId, 0);
      __syncthreads();
      for (int j = chunkId; j <= tile; j += NCH) {
        if (j + NCH <= tile) stage(j + NCH, cur ^ 1);

        const short* lkh = ls_kh + cur * 8192;
        const short* lkl = ls_kl + cur * 8192;
        const short* lv  = ls_v  + cur * 8192;

        // ---- QK^T: 4 products (hi*hi + lo*hi + hi*lo + lo*lo) => ~fp32-accurate scores
        f32x4 s[4];
#pragma unroll
        for (int ct = 0; ct < 4; ++ct) {
          f32x4 a = f32x4{0.f, 0.f, 0.f, 0.f};
          const int row = ct * 16 + cl;
#pragma unroll
          for (int kc = 0; kc < 4; ++kc) {
            const int byte = (row << 8) + ((((kc << 2) + g4) ^ (row & 7)) << 4);
            bf16x8 kh = *(const bf16x8*)((const char*)lkh + byte);
            bf16x8 kl = *(const bf16x8*)((const char*)lkl + byte);
            a = __builtin_amdgcn_mfma_f32_16x16x32_bf16(qh[kc], kh, a, 0, 0, 0);
            a = __builtin_amdgcn_mfma_f32_16x16x32_bf16(ql[kc], kh, a, 0, 0, 0);
            a = __builtin_amdgcn_mfma_f32_16x16x32_bf16(qh[kc], kl, a, 0, 0, 0);
            a = __builtin_amdgcn_mfma_f32_16x16x32_bf16(ql[kc], kl, a, 0, 0, 0);
          }
          s[ct] = a;
        }

        // causal mask on the diagonal tile
        if (j == tile) {
          const int qr = w * 16 + g4 * 4;
#pragma unroll
          for (int ct = 0; ct < 4; ++ct)
#pragma unroll
            for (int r = 0; r < 4; ++r)
              if (ct * 16 + cl > qr + r) s[ct][r] = -1e30f;
        }

        // online softmax (rows live in the cl-group of 16 lanes)
#pragma unroll
        for (int r = 0; r < 4; ++r) {
          float rm = fmaxf(fmaxf(s[0][r], s[1][r]), fmaxf(s[2][r], s[3][r]));
          rm = fmaxf(rm, __shfl_xor(rm, 1));
          rm = fmaxf(rm, __shfl_xor(rm, 2));
          rm = fmaxf(rm, __shfl_xor(rm, 4));
          rm = fmaxf(rm, __shfl_xor(rm, 8));
          float mnew = fmaxf(m_r[r], rm);
          float corr = __expf(m_r[r] - mnew);
          float rs = 0.f;
#pragma unroll
          for (int ct = 0; ct < 4; ++ct) {
            float p = __expf(s[ct][r] - mnew);
            s[ct][r] = p;
            rs += p;
          }
          rs += __shfl_xor(rs, 1);
          rs += __shfl_xor(rs, 2);
          rs += __shfl_xor(rs, 4);
          rs += __shfl_xor(rs, 8);
          l_r[r] = l_r[r] * corr + rs;
          m_r[r] = mnew;
#pragma unroll
          for (int c2 = 0; c2 < 8; ++c2) o_acc[c2][r] *= corr;
        }

        // P -> bf16, round-trip through wave-private LDS to A-layout
#pragma unroll
        for (int ct = 0; ct < 4; ++ct)
#pragma unroll
          for (int r = 0; r < 4; ++r)
            ((unsigned short*)pw)[(g4 * 4 + r) * 72 + ct * 16 + cl] = f2bf(s[ct][r]);

        bf16x8 pa0 = *(const bf16x8*)((const char*)pw + cl * 144 + g4 * 16);
        bf16x8 pa1 = *(const bf16x8*)((const char*)pw + cl * 144 + 64 + g4 * 16);

        // ---- PV: o += P @ V  (V^T in LDS, B-layout reads)
#pragma unroll
        for (int c2 = 0; c2 < 8; ++c2) {
          const int d = c2 * 16 + cl;
#pragma unroll
          for (int kc2 = 0; kc2 < 2; ++kc2) {
            const int byte = (d << 7) + ((((kc2 << 2) + g4) ^ (d & 7)) << 4);
            bf16x8 vb = *(const bf16x8*)((const char*)lv + byte);
            o_acc[c2] = __builtin_amdgcn_mfma_f32_16x16x32_bf16(kc2 ? pa1 : pa0, vb, o_acc[c2], 0, 0, 0);
          }
        }

        __syncthreads();
        cur ^= 1;
      }
    }

    // write partials (unnormalized o, m, l)
    const int base = tile * NCH + chunkId;
#pragma unroll
    for (int c2 = 0; c2 < 8; ++c2)
#pragma unroll
      for (int r = 0; r < 4; ++r)
        part_o[((size_t)base * QT + w * 16 + g4 * 4 + r) * HD + c2 * 16 + cl] = o_acc[c2][r];
    if (cl == 0) {
#pragma unroll
      for (int r = 0; r < 4; ++r) {
        part_ml[base * 128 + w * 16 + g4 * 4 + r]      = m_r[r];
        part_ml[base * 128 + 64 + w * 16 + g4 * 4 + r] = l_r[r];
      }
    }
  }
}

// ---------------- merge the 4 column-chunk partials ----------------
__global__ __launch_bounds__(128)
void merge_kernel(const float* __restrict__ part_o, const float* __restrict__ part_ml,
                  float* __restrict__ out)
{
  const int row  = blockIdx.x;
  const int tile = row >> 6;
  const int r    = row & 63;
  const int c    = threadIdx.x;

  float m[4], l[4];
  float mstar = -3e38f;
#pragma unroll
  for (int s = 0; s < 4; ++s) {
    m[s] = part_ml[(tile * 4 + s) * 128 + r];
    l[s] = part_ml[(tile * 4 + s) * 128 + 64 + r];
    mstar = fmaxf(mstar, m[s]);
  }
  float num = 0.f, den = 0.f;
#pragma unroll
  for (int s = 0; s < 4; ++s) {
    float wgt = __expf(m[s] - mstar);
    den += l[s] * wgt;
    num += wgt * part_o[((size_t)(tile * 4 + s) * QT + r) * HD + c];
  }
  out[(size_t)row * HD + c] = num / den;
}

extern "C" void kernel_launch(void* const* d_in, const int* in_sizes, int n_in,
                              void* d_out, int out_size, void* d_ws, size_t ws_size,
                              hipStream_t stream)
{
  const float* x  = (const float*)d_in[0];
  const float* wq = (const float*)d_in[1];
  const float* wk = (const float*)d_in[2];
  const float* wv = (const float*)d_in[3];
  float* out = (float*)d_out;

  unsigned short* q_hi = (unsigned short*)d_ws;          // each S*HD = 1048576 elems
  unsigned short* q_lo = q_hi + (size_t)S_LEN * HD;
  unsigned short* k_hi = q_lo + (size_t)S_LEN * HD;
  unsigned short* k_lo = k_hi + (size_t)S_LEN * HD;
  unsigned short* vT   = k_lo + (size_t)S_LEN * HD;
  float* part_o  = (float*)(vT + (size_t)S_LEN * HD);    // 512*64*128
  float* part_ml = part_o + (size_t)512 * QT * HD;       // 512*128

  proj_kernel<<<dim3(64, 3), 256, 0, stream>>>(x, wq, wk, wv,
                                               q_hi, q_lo, k_hi, k_lo, vT);
  const int smem_bytes = (16384 * 3 + 4 * 16 * 72) * (int)sizeof(short);
  attn_kernel<<<dim3(256), 256, smem_bytes, stream>>>(q_hi, q_lo, k_hi, k_lo, vT,
                                                      part_o, part_ml);
  merge_kernel<<<dim3(8192), 128, 0, stream>>>(part_o, part_ml, out);
}

// Round 3
// 164.364 us; speedup vs baseline: 4.8941x; 2.7741x over previous
//
#include <hip/hip_runtime.h>

#define S_LEN 8192
#define D_DIM 2048
#define HD    128
#define NT    128      // number of 64-row tiles
#define QT    64
#define NCH   4        // kv chunks (flash-decoding split)

typedef __attribute__((ext_vector_type(8))) short bf16x8;
typedef __attribute__((ext_vector_type(4))) float f32x4;

__device__ __forceinline__ unsigned short f2bf(float f) {
  unsigned int u = __float_as_uint(f);
  u += 0x7fffu + ((u >> 16) & 1u);
  return (unsigned short)(u >> 16);
}
__device__ __forceinline__ float bf2f(unsigned short h) {
  return __uint_as_float(((unsigned int)h) << 16);
}

__device__ __forceinline__ void glds16(const void* g, const short* l) {
  __builtin_amdgcn_global_load_lds(
      (const __attribute__((address_space(1))) void*)g,
      (__attribute__((address_space(3))) void*)l, 16, 0, 0);
}

// ---------------- split x into hi/lo bf16 ----------------
__global__ __launch_bounds__(256)
void split_x_kernel(const float* __restrict__ x,
                    unsigned short* __restrict__ xh, unsigned short* __restrict__ xl)
{
  const size_t n4 = (size_t)S_LEN * D_DIM / 4;
  size_t idx = (size_t)blockIdx.x * 256 + threadIdx.x;
  const size_t stride = (size_t)gridDim.x * 256;
  for (; idx < n4; idx += stride) {
    float4 v = ((const float4*)x)[idx];
    ushort4 h, l;
#pragma unroll
    for (int j = 0; j < 4; ++j) {
      float f = ((const float*)&v)[j];
      unsigned short hb = f2bf(f);
      ((unsigned short*)&h)[j] = hb;
      ((unsigned short*)&l)[j] = f2bf(f - bf2f(hb));
    }
    ((ushort4*)xh)[idx] = h;
    ((ushort4*)xl)[idx] = l;
  }
}

// ---------------- transpose+split w: wT[mode][col][k] hi/lo bf16 ----------------
__global__ __launch_bounds__(256)
void split_w_kernel(const float* __restrict__ wq, const float* __restrict__ wk,
                    const float* __restrict__ wv,
                    unsigned short* __restrict__ wTh, unsigned short* __restrict__ wTl)
{
  const int mode = blockIdx.y;
  const float* __restrict__ w = (mode == 0) ? wq : (mode == 1) ? wk : wv;
  unsigned short* __restrict__ oh = wTh + (size_t)mode * HD * D_DIM;
  unsigned short* __restrict__ ol = wTl + (size_t)mode * HD * D_DIM;
  const int k0 = blockIdx.x * 64;

  __shared__ float ws[64][132];
  const int t = threadIdx.x;
#pragma unroll
  for (int i = 0; i < 8; ++i) {
    int idx = t + i * 256;
    int row = idx >> 5;
    int c4  = idx & 31;
    *(float4*)&ws[row][c4 * 4] = *(const float4*)(w + (size_t)(k0 + row) * HD + c4 * 4);
  }
  __syncthreads();
#pragma unroll
  for (int i = 0; i < 4; ++i) {
    int task = t + i * 256;
    int col = task >> 3;
    int kc  = task & 7;
    ushort4 h[2], l[2];
#pragma unroll
    for (int e = 0; e < 8; ++e) {
      float f = ws[kc * 8 + e][col];
      unsigned short hb = f2bf(f);
      ((unsigned short*)&h[e >> 2])[e & 3] = hb;
      ((unsigned short*)&l[e >> 2])[e & 3] = f2bf(f - bf2f(hb));
    }
    size_t off = (size_t)col * D_DIM + k0 + kc * 8;
    *(ushort4*)(oh + off)     = h[0];
    *(ushort4*)(oh + off + 4) = h[1];
    *(ushort4*)(ol + off)     = l[0];
    *(ushort4*)(ol + off + 4) = l[1];
  }
}

// ---------------- projection GEMM: split-bf16 MFMA ----------------
// tile 64(M) x 128(N), BK=32, 4 waves each 32x64; q/k: 3 products, v: 1 product
// LDS per buffer (shorts): [XH 2048][XL 2048][WH 4096][WL 4096]
__global__ __launch_bounds__(256)
void proj_kernel(const unsigned short* __restrict__ xh, const unsigned short* __restrict__ xl,
                 const unsigned short* __restrict__ wTh, const unsigned short* __restrict__ wTl,
                 unsigned short* __restrict__ q_hi, unsigned short* __restrict__ q_lo,
                 unsigned short* __restrict__ k_hi, unsigned short* __restrict__ k_lo,
                 unsigned short* __restrict__ vT)
{
  __shared__ short sm[2][12288];

  const int mode = blockIdx.y;
  const int mt   = blockIdx.x;
  const bool split = (mode < 2);

  const unsigned short* gxh = xh + (size_t)mt * 64 * D_DIM;
  const unsigned short* gxl = xl + (size_t)mt * 64 * D_DIM;
  const unsigned short* gwh = wTh + (size_t)mode * HD * D_DIM;
  const unsigned short* gwl = wTl + (size_t)mode * HD * D_DIM;

  const int t   = threadIdx.x;
  const int wid = t >> 6;
  const int ln  = t & 63;
  const int cl  = ln & 15;
  const int g4  = ln >> 4;

  auto stage = [&](int kt, int buf) {
    short* b = sm[buf];
    {
      int slot = wid * 64 + ln;
      int row = slot >> 2, sc = slot & 3;
      int kof = (sc ^ (row & 3)) * 8;
      glds16(gxh + (size_t)row * D_DIM + kt + kof, b + wid * 512);
      if (split)
        glds16(gxl + (size_t)row * D_DIM + kt + kof, b + 2048 + wid * 512);
    }
#pragma unroll
    for (int g = 0; g < 2; ++g) {
      int slot = g * 256 + wid * 64 + ln;
      int col = slot >> 2, sc = slot & 3;
      int kof = (sc ^ (col & 3)) * 8;
      glds16(gwh + (size_t)col * D_DIM + kt + kof, b + 4096 + (g * 256 + wid * 64) * 8);
      if (split)
        glds16(gwl + (size_t)col * D_DIM + kt + kof, b + 8192 + (g * 256 + wid * 64) * 8);
    }
  };

  f32x4 acc[2][4];
#pragma unroll
  for (int m = 0; m < 2; ++m)
#pragma unroll
    for (int n = 0; n < 4; ++n) acc[m][n] = f32x4{0.f, 0.f, 0.f, 0.f};

  stage(0, 0);
  __syncthreads();

  for (int kt = 0, step = 0; kt < D_DIM; kt += 32, ++step) {
    const int cur = step & 1;
    if (kt + 32 < D_DIM) stage(kt + 32, cur ^ 1);

    const short* b = sm[cur];
    bf16x8 a_h[2], a_l[2], b_h[4], b_l[4];
#pragma unroll
    for (int m = 0; m < 2; ++m) {
      int row = (wid >> 1) * 32 + m * 16 + cl;
      int byte = row * 64 + ((g4 ^ (row & 3)) << 4);
      a_h[m] = *(const bf16x8*)((const char*)b + byte);
      if (split) a_l[m] = *(const bf16x8*)((const char*)b + 4096 + byte);
    }
#pragma unroll
    for (int n = 0; n < 4; ++n) {
      int col = (wid & 1) * 64 + n * 16 + cl;
      int byte = col * 64 + ((g4 ^ (col & 3)) << 4);
      b_h[n] = *(const bf16x8*)((const char*)b + 8192 + byte);
      if (split) b_l[n] = *(const bf16x8*)((const char*)b + 16384 + byte);
    }

#pragma unroll
    for (int m = 0; m < 2; ++m)
#pragma unroll
      for (int n = 0; n < 4; ++n)
        acc[m][n] = __builtin_amdgcn_mfma_f32_16x16x32_bf16(a_h[m], b_h[n], acc[m][n], 0, 0, 0);
    if (split) {
#pragma unroll
      for (int m = 0; m < 2; ++m)
#pragma unroll
        for (int n = 0; n < 4; ++n) {
          acc[m][n] = __builtin_amdgcn_mfma_f32_16x16x32_bf16(a_l[m], b_h[n], acc[m][n], 0, 0, 0);
          acc[m][n] = __builtin_amdgcn_mfma_f32_16x16x32_bf16(a_h[m], b_l[n], acc[m][n], 0, 0, 0);
        }
    }
    __syncthreads();
  }

  const int rbase = mt * 64 + (wid >> 1) * 32 + g4 * 4;
  const int cbase = (wid & 1) * 64 + cl;

  if (mode < 2) {
    const float scale = (mode == 0) ? 0.08838834764831843f : 1.0f;
    unsigned short* __restrict__ oh = (mode == 0) ? q_hi : k_hi;
    unsigned short* __restrict__ ol = (mode == 0) ? q_lo : k_lo;
#pragma unroll
    for (int m = 0; m < 2; ++m)
#pragma unroll
      for (int n = 0; n < 4; ++n)
#pragma unroll
        for (int r = 0; r < 4; ++r) {
          float val = acc[m][n][r] * scale;
          unsigned short hb = f2bf(val);
          size_t off = (size_t)(rbase + m * 16 + r) * HD + cbase + n * 16;
          oh[off] = hb;
          ol[off] = f2bf(val - bf2f(hb));
        }
  } else {
#pragma unroll
    for (int m = 0; m < 2; ++m)
#pragma unroll
      for (int n = 0; n < 4; ++n) {
        ushort4 o;
#pragma unroll
        for (int r = 0; r < 4; ++r) ((unsigned short*)&o)[r] = f2bf(acc[m][n][r]);
        int col = cbase + n * 16;
        *(ushort4*)(vT + (size_t)col * S_LEN + rbase + m * 16) = o;
      }
  }
}

// ---------------- MFMA flash attention (split-bf16 QK^T, bf16 PV) ----------------
__global__ __launch_bounds__(256)
void attn_kernel(const unsigned short* __restrict__ q_hi, const unsigned short* __restrict__ q_lo,
                 const unsigned short* __restrict__ k_hi, const unsigned short* __restrict__ k_lo,
                 const unsigned short* __restrict__ vT,
                 float* __restrict__ part_o, float* __restrict__ part_ml)
{
  extern __shared__ short smem[];
  short* ls_kh = smem;                 // 2 x 64x128 bf16 (XOR-swizzled)
  short* ls_kl = ls_kh + 16384;
  short* ls_v  = ls_kl + 16384;        // 2 x 128x64 bf16 (v^T, XOR-swizzled)
  short* ls_p  = ls_v + 16384;         // 4 waves x [16][72] bf16

  const int t   = threadIdx.x;
  const int w   = t >> 6;
  const int ln  = t & 63;
  const int cl  = ln & 15;
  const int g4  = ln >> 4;
  const int pairId  = blockIdx.x >> 2;
  const int chunkId = blockIdx.x & 3;

  short* pw = ls_p + w * (16 * 72);

  auto stage = [&](int j, int buf) {
    const unsigned short* gkh = k_hi + (size_t)j * QT * HD;
    const unsigned short* gkl = k_lo + (size_t)j * QT * HD;
    const unsigned short* gv  = vT + (size_t)j * QT;
    const short* lkh = ls_kh + buf * 8192;
    const short* lkl = ls_kl + buf * 8192;
    const short* lv  = ls_v  + buf * 8192;
#pragma unroll
    for (int i = 0; i < 4; ++i) {
      int slot = w * 256 + i * 64 + ln;
      int row = slot >> 4, sc = slot & 15;
      int c16 = sc ^ (row & 7);
      glds16(gkh + row * HD + c16 * 8, lkh + (w * 256 + i * 64) * 8);
      glds16(gkl + row * HD + c16 * 8, lkl + (w * 256 + i * 64) * 8);
    }
#pragma unroll
    for (int i = 0; i < 4; ++i) {
      int slot = w * 256 + i * 64 + ln;
      int d = slot >> 3, sc = slot & 7;
      int c = sc ^ (d & 7);
      glds16(gv + (size_t)d * S_LEN + c * 8, lv + (w * 256 + i * 64) * 8);
    }
  };

  for (int hh = 0; hh < 2; ++hh) {
    const int tile = hh ? (NT - 1 - pairId) : pairId;

    bf16x8 qh[4], ql[4];
    {
      const size_t qoff = ((size_t)tile * QT + w * 16 + cl) * HD + g4 * 8;
#pragma unroll
      for (int kc = 0; kc < 4; ++kc) {
        qh[kc] = *(const bf16x8*)(q_hi + qoff + kc * 32);
        ql[kc] = *(const bf16x8*)(q_lo + qoff + kc * 32);
      }
    }

    float m_r[4], l_r[4];
    f32x4 o_acc[8];
#pragma unroll
    for (int r = 0; r < 4; ++r) { m_r[r] = -1e30f; l_r[r] = 0.f; }
#pragma unroll
    for (int c = 0; c < 8; ++c) o_acc[c] = f32x4{0.f, 0.f, 0.f, 0.f};

    if (chunkId <= tile) {
      int cur = 0;
      stage(chunkId, 0);
      __syncthreads();
      for (int j = chunkId; j <= tile; j += NCH) {
        if (j + NCH <= tile) stage(j + NCH, cur ^ 1);

        const short* lkh = ls_kh + cur * 8192;
        const short* lkl = ls_kl + cur * 8192;
        const short* lv  = ls_v  + cur * 8192;

        f32x4 s[4];
#pragma unroll
        for (int ct = 0; ct < 4; ++ct) {
          f32x4 a = f32x4{0.f, 0.f, 0.f, 0.f};
          const int row = ct * 16 + cl;
#pragma unroll
          for (int kc = 0; kc < 4; ++kc) {
            const int byte = (row << 8) + ((((kc << 2) + g4) ^ (row & 7)) << 4);
            bf16x8 kh = *(const bf16x8*)((const char*)lkh + byte);
            bf16x8 kl = *(const bf16x8*)((const char*)lkl + byte);
            a = __builtin_amdgcn_mfma_f32_16x16x32_bf16(qh[kc], kh, a, 0, 0, 0);
            a = __builtin_amdgcn_mfma_f32_16x16x32_bf16(ql[kc], kh, a, 0, 0, 0);
            a = __builtin_amdgcn_mfma_f32_16x16x32_bf16(qh[kc], kl, a, 0, 0, 0);
            a = __builtin_amdgcn_mfma_f32_16x16x32_bf16(ql[kc], kl, a, 0, 0, 0);
          }
          s[ct] = a;
        }

        if (j == tile) {
          const int qr = w * 16 + g4 * 4;
#pragma unroll
          for (int ct = 0; ct < 4; ++ct)
#pragma unroll
            for (int r = 0; r < 4; ++r)
              if (ct * 16 + cl > qr + r) s[ct][r] = -1e30f;
        }

#pragma unroll
        for (int r = 0; r < 4; ++r) {
          float rm = fmaxf(fmaxf(s[0][r], s[1][r]), fmaxf(s[2][r], s[3][r]));
          rm = fmaxf(rm, __shfl_xor(rm, 1));
          rm = fmaxf(rm, __shfl_xor(rm, 2));
          rm = fmaxf(rm, __shfl_xor(rm, 4));
          rm = fmaxf(rm, __shfl_xor(rm, 8));
          float mnew = fmaxf(m_r[r], rm);
          float corr = __expf(m_r[r] - mnew);
          float rs = 0.f;
#pragma unroll
          for (int ct = 0; ct < 4; ++ct) {
            float p = __expf(s[ct][r] - mnew);
            s[ct][r] = p;
            rs += p;
          }
          rs += __shfl_xor(rs, 1);
          rs += __shfl_xor(rs, 2);
          rs += __shfl_xor(rs, 4);
          rs += __shfl_xor(rs, 8);
          l_r[r] = l_r[r] * corr + rs;
          m_r[r] = mnew;
#pragma unroll
          for (int c2 = 0; c2 < 8; ++c2) o_acc[c2][r] *= corr;
        }

#pragma unroll
        for (int ct = 0; ct < 4; ++ct)
#pragma unroll
          for (int r = 0; r < 4; ++r)
            ((unsigned short*)pw)[(g4 * 4 + r) * 72 + ct * 16 + cl] = f2bf(s[ct][r]);

        bf16x8 pa0 = *(const bf16x8*)((const char*)pw + cl * 144 + g4 * 16);
        bf16x8 pa1 = *(const bf16x8*)((const char*)pw + cl * 144 + 64 + g4 * 16);

#pragma unroll
        for (int c2 = 0; c2 < 8; ++c2) {
          const int d = c2 * 16 + cl;
#pragma unroll
          for (int kc2 = 0; kc2 < 2; ++kc2) {
            const int byte = (d << 7) + ((((kc2 << 2) + g4) ^ (d & 7)) << 4);
            bf16x8 vb = *(const bf16x8*)((const char*)lv + byte);
            o_acc[c2] = __builtin_amdgcn_mfma_f32_16x16x32_bf16(kc2 ? pa1 : pa0, vb, o_acc[c2], 0, 0, 0);
          }
        }

        __syncthreads();
        cur ^= 1;
      }
    }

    const int base = tile * NCH + chunkId;
#pragma unroll
    for (int c2 = 0; c2 < 8; ++c2)
#pragma unroll
      for (int r = 0; r < 4; ++r)
        part_o[((size_t)base * QT + w * 16 + g4 * 4 + r) * HD + c2 * 16 + cl] = o_acc[c2][r];
    if (cl == 0) {
#pragma unroll
      for (int r = 0; r < 4; ++r) {
        part_ml[base * 128 + w * 16 + g4 * 4 + r]      = m_r[r];
        part_ml[base * 128 + 64 + w * 16 + g4 * 4 + r] = l_r[r];
      }
    }
  }
}

// ---------------- merge the 4 column-chunk partials ----------------
__global__ __launch_bounds__(128)
void merge_kernel(const float* __restrict__ part_o, const float* __restrict__ part_ml,
                  float* __restrict__ out)
{
  const int row  = blockIdx.x;
  const int tile = row >> 6;
  const int r    = row & 63;
  const int c    = threadIdx.x;

  float m[4], l[4];
  float mstar = -3e38f;
#pragma unroll
  for (int s = 0; s < 4; ++s) {
    m[s] = part_ml[(tile * 4 + s) * 128 + r];
    l[s] = part_ml[(tile * 4 + s) * 128 + 64 + r];
    mstar = fmaxf(mstar, m[s]);
  }
  float num = 0.f, den = 0.f;
#pragma unroll
  for (int s = 0; s < 4; ++s) {
    float wgt = __expf(m[s] - mstar);
    den += l[s] * wgt;
    num += wgt * part_o[((size_t)(tile * 4 + s) * QT + r) * HD + c];
  }
  out[(size_t)row * HD + c] = num / den;
}

extern "C" void kernel_launch(void* const* d_in, const int* in_sizes, int n_in,
                              void* d_out, int out_size, void* d_ws, size_t ws_size,
                              hipStream_t stream)
{
  const float* x  = (const float*)d_in[0];
  const float* wq = (const float*)d_in[1];
  const float* wk = (const float*)d_in[2];
  const float* wv = (const float*)d_in[3];
  float* out = (float*)d_out;

  unsigned short* p = (unsigned short*)d_ws;
  unsigned short* xh = p;  p += (size_t)S_LEN * D_DIM;       // 16.7M shorts
  unsigned short* xl = p;  p += (size_t)S_LEN * D_DIM;
  unsigned short* wTh = p; p += (size_t)3 * HD * D_DIM;
  unsigned short* wTl = p; p += (size_t)3 * HD * D_DIM;
  unsigned short* q_hi = p; p += (size_t)S_LEN * HD;
  unsigned short* q_lo = p; p += (size_t)S_LEN * HD;
  unsigned short* k_hi = p; p += (size_t)S_LEN * HD;
  unsigned short* k_lo = p; p += (size_t)S_LEN * HD;
  unsigned short* vT   = p; p += (size_t)S_LEN * HD;
  float* part_o  = (float*)p;                                 // 512*64*128
  float* part_ml = part_o + (size_t)512 * QT * HD;            // 512*128

  split_x_kernel<<<4096, 256, 0, stream>>>(x, xh, xl);
  split_w_kernel<<<dim3(32, 3), 256, 0, stream>>>(wq, wk, wv, wTh, wTl);
  proj_kernel<<<dim3(128, 3), 256, 0, stream>>>(xh, xl, wTh, wTl,
                                                q_hi, q_lo, k_hi, k_lo, vT);
  const int smem_bytes = (16384 * 3 + 4 * 16 * 72) * (int)sizeof(short);
  attn_kernel<<<dim3(256), 256, smem_bytes, stream>>>(q_hi, q_lo, k_hi, k_lo, vT,
                                                      part_o, part_ml);
  merge_kernel<<<dim3(8192), 128, 0, stream>>>(part_o, part_ml, out);
}